// Round 2
// baseline (4032.157 us; speedup 1.0000x reference)
//
#include <hip/hip_runtime.h>
#include <cstdint>

// GF(2) encoder: out[b][n] = parity( x_row[b] & g_row[n] ), bit-packed.
// B=131072, K=512, N=1024.
//
// Packing scheme (component-major, applied identically to x and G so parity
// is invariant): a 256-float chunk handled by one wave becomes 4 u64 words,
// word j bit i = (chunk[i*4 + j] != 0). Row of K=512 floats = 2 chunks =
// 8 u64 = 16 u32, contiguous.

// ---------------------------------------------------------------------------
// Pack G: one wave per 256-float chunk. nChunks = N*K/256 = 2048.
__global__ void pack256_kernel(const float* __restrict__ in,
                               unsigned long long* __restrict__ out,
                               int nChunks) {
    const int chunk = blockIdx.x * (blockDim.x >> 6) + (threadIdx.x >> 6);
    const int lane = threadIdx.x & 63;
    if (chunk >= nChunks) return;
    const float4 v = reinterpret_cast<const float4*>(in + (size_t)chunk * 256)[lane];
    unsigned long long m0 = __ballot(v.x != 0.0f);
    unsigned long long m1 = __ballot(v.y != 0.0f);
    unsigned long long m2 = __ballot(v.z != 0.0f);
    unsigned long long m3 = __ballot(v.w != 0.0f);
    if (lane == 0) {
        unsigned long long* o = out + (size_t)chunk * 4;
        o[0] = m0; o[1] = m1; o[2] = m2; o[3] = m3;
    }
}

// ---------------------------------------------------------------------------
// Fused: per block of 256 threads, pack 64 rows of x into LDS (4 KiB), then
// each thread computes 4 columns for all 64 rows. G rows live in registers.
__global__ __launch_bounds__(256, 3) void gf2_fused_kernel(
    const float* __restrict__ x,      // [B][512] 0/1 floats
    const uint32_t* __restrict__ gp,  // [N][16] packed G rows
    float* __restrict__ out) {        // [B][1024]
    __shared__ unsigned long long xl[64 * 8];  // 64 rows x 8 u64 = 4 KiB

    const int tid = threadIdx.x;
    const int lane = tid & 63;
    const int wv = tid >> 6;                 // wave id 0..3
    const long long b0 = (long long)blockIdx.x * 64;

    // This thread's 4 G rows (64 VGPRs), issued early to overlap with pack.
    uint32_t g[4][16];
#pragma unroll
    for (int j = 0; j < 4; ++j) {
        const uint4* gr = reinterpret_cast<const uint4*>(gp + (size_t)(tid * 4 + j) * 16);
        uint4 a = gr[0], b = gr[1], c = gr[2], d = gr[3];
        g[j][0] = a.x;  g[j][1] = a.y;  g[j][2] = a.z;  g[j][3] = a.w;
        g[j][4] = b.x;  g[j][5] = b.y;  g[j][6] = b.z;  g[j][7] = b.w;
        g[j][8] = c.x;  g[j][9] = c.y;  g[j][10] = c.z; g[j][11] = c.w;
        g[j][12] = d.x; g[j][13] = d.y; g[j][14] = d.z; g[j][15] = d.w;
    }

    // Pack phase: 128 chunks of 256 floats; wave wv takes chunks wv, wv+4, ...
    const float* xb = x + b0 * 512;
#pragma unroll 4
    for (int c4 = 0; c4 < 32; ++c4) {
        const int c = c4 * 4 + wv;
        const float4 v = reinterpret_cast<const float4*>(xb + (size_t)c * 256)[lane];
        unsigned long long m0 = __ballot(v.x != 0.0f);
        unsigned long long m1 = __ballot(v.y != 0.0f);
        unsigned long long m2 = __ballot(v.z != 0.0f);
        unsigned long long m3 = __ballot(v.w != 0.0f);
        if (lane == 0) {
            xl[c * 4 + 0] = m0; xl[c * 4 + 1] = m1;
            xl[c * 4 + 2] = m2; xl[c * 4 + 3] = m3;
        }
    }
    __syncthreads();

    // Compute phase: 64 rows; x row via broadcast ds_read_b128 (conflict-free).
#pragma unroll 2
    for (int r = 0; r < 64; ++r) {
        const uint4* xr = reinterpret_cast<const uint4*>(xl) + r * 4;
        uint4 q0 = xr[0], q1 = xr[1], q2 = xr[2], q3 = xr[3];
        uint32_t xv[16] = {q0.x, q0.y, q0.z, q0.w,
                           q1.x, q1.y, q1.z, q1.w,
                           q2.x, q2.y, q2.z, q2.w,
                           q3.x, q3.y, q3.z, q3.w};
        uint32_t a0 = 0, a1 = 0, a2 = 0, a3 = 0;
#pragma unroll
        for (int i = 0; i < 16; ++i) {
            a0 ^= xv[i] & g[0][i];
            a1 ^= xv[i] & g[1][i];
            a2 ^= xv[i] & g[2][i];
            a3 ^= xv[i] & g[3][i];
        }
        float4 o;
        o.x = (float)(__popc(a0) & 1);
        o.y = (float)(__popc(a1) & 1);
        o.z = (float)(__popc(a2) & 1);
        o.w = (float)(__popc(a3) & 1);
        reinterpret_cast<float4*>(out + (size_t)(b0 + r) * 1024)[tid] = o;
    }
}

// ---------------------------------------------------------------------------
extern "C" void kernel_launch(void* const* d_in, const int* in_sizes, int n_in,
                              void* d_out, int out_size, void* d_ws, size_t ws_size,
                              hipStream_t stream) {
    const float* x = (const float*)d_in[0];   // [B][512]
    const float* G = (const float*)d_in[1];   // [N][512]
    float* out = (float*)d_out;

    const int B = 131072;
    // Pack G: 2048 chunks, 4 chunks (waves) per block -> 512 blocks.
    unsigned long long* gp64 = (unsigned long long*)d_ws;  // 64 KiB
    pack256_kernel<<<512, 256, 0, stream>>>(G, gp64, 2048);
    // Fused pack-x + encode: one block per 64 rows.
    gf2_fused_kernel<<<B / 64, 256, 0, stream>>>(
        x, (const uint32_t*)gp64, out);
}

// Round 3
// 226.046 us; speedup vs baseline: 17.8378x; 17.8378x over previous
//
#include <hip/hip_runtime.h>
#include <cstdint>

// GF(2) encoder: out[b][n] = parity( x_row[b] & g_row[n] ), bit-packed.
// B=131072, K=512, N=1024.
//
// Packing scheme (component-major, identical for x and G so parity is
// invariant): a 256-float chunk handled by one wave becomes 4 u64 words,
// word j bit i = (chunk[i*4 + j] != 0). Row of K=512 floats = 2 chunks =
// 8 u64 = 16 u32, contiguous.
//
// R2 lesson: g[4][16]=64 VGPRs + __launch_bounds__(256,3) forced a spill
// (VGPR_Count=84 < ~90 live) -> scratch thrash, 12.4 GB HBM, 4 ms.
// R3: 512 threads x 2 cols/thread -> g[2][16]=32 VGPRs, ~60 live, no
// occupancy hint. No spill, 8 waves/SIMD possible.

// ---------------------------------------------------------------------------
// Pack G: one wave per 256-float chunk. nChunks = N*K/256 = 2048.
__global__ void pack256_kernel(const float* __restrict__ in,
                               unsigned long long* __restrict__ out,
                               int nChunks) {
    const int chunk = blockIdx.x * (blockDim.x >> 6) + (threadIdx.x >> 6);
    const int lane = threadIdx.x & 63;
    if (chunk >= nChunks) return;
    const float4 v = reinterpret_cast<const float4*>(in + (size_t)chunk * 256)[lane];
    unsigned long long m0 = __ballot(v.x != 0.0f);
    unsigned long long m1 = __ballot(v.y != 0.0f);
    unsigned long long m2 = __ballot(v.z != 0.0f);
    unsigned long long m3 = __ballot(v.w != 0.0f);
    if (lane == 0) {
        unsigned long long* o = out + (size_t)chunk * 4;
        o[0] = m0; o[1] = m1; o[2] = m2; o[3] = m3;
    }
}

// ---------------------------------------------------------------------------
// Fused: block of 512 threads packs 64 rows of x into LDS (4 KiB), then each
// thread computes 2 columns for all 64 rows. G rows (2x16 u32) in registers.
__global__ __launch_bounds__(512) void gf2_fused_kernel(
    const float* __restrict__ x,      // [B][512] 0/1 floats
    const uint32_t* __restrict__ gp,  // [N][16] packed G rows
    float* __restrict__ out) {        // [B][1024]
    __shared__ unsigned long long xl[64 * 8];  // 64 rows x 8 u64 = 4 KiB

    const int tid = threadIdx.x;
    const int lane = tid & 63;
    const int wv = tid >> 6;                 // wave id 0..7
    const long long b0 = (long long)blockIdx.x * 64;

    // This thread's 2 G rows (32 VGPRs).
    uint32_t g[2][16];
#pragma unroll
    for (int j = 0; j < 2; ++j) {
        const uint4* gr = reinterpret_cast<const uint4*>(gp + (size_t)(tid * 2 + j) * 16);
        uint4 a = gr[0], b = gr[1], c = gr[2], d = gr[3];
        g[j][0] = a.x;  g[j][1] = a.y;  g[j][2] = a.z;  g[j][3] = a.w;
        g[j][4] = b.x;  g[j][5] = b.y;  g[j][6] = b.z;  g[j][7] = b.w;
        g[j][8] = c.x;  g[j][9] = c.y;  g[j][10] = c.z; g[j][11] = c.w;
        g[j][12] = d.x; g[j][13] = d.y; g[j][14] = d.z; g[j][15] = d.w;
    }

    // Pack phase: 128 chunks of 256 floats; wave wv takes chunks wv, wv+8, ...
    const float* xb = x + b0 * 512;
#pragma unroll
    for (int c8 = 0; c8 < 16; ++c8) {
        const int c = c8 * 8 + wv;
        const float4 v = reinterpret_cast<const float4*>(xb + (size_t)c * 256)[lane];
        unsigned long long m0 = __ballot(v.x != 0.0f);
        unsigned long long m1 = __ballot(v.y != 0.0f);
        unsigned long long m2 = __ballot(v.z != 0.0f);
        unsigned long long m3 = __ballot(v.w != 0.0f);
        if (lane == 0) {
            xl[c * 4 + 0] = m0; xl[c * 4 + 1] = m1;
            xl[c * 4 + 2] = m2; xl[c * 4 + 3] = m3;
        }
    }
    __syncthreads();

    // Compute phase: 64 rows; x row via broadcast ds_read_b128 (conflict-free).
#pragma unroll 2
    for (int r = 0; r < 64; ++r) {
        const uint4* xr = reinterpret_cast<const uint4*>(xl) + r * 4;
        uint4 q0 = xr[0], q1 = xr[1], q2 = xr[2], q3 = xr[3];
        uint32_t xv[16] = {q0.x, q0.y, q0.z, q0.w,
                           q1.x, q1.y, q1.z, q1.w,
                           q2.x, q2.y, q2.z, q2.w,
                           q3.x, q3.y, q3.z, q3.w};
        uint32_t a0 = 0, a1 = 0;
#pragma unroll
        for (int i = 0; i < 16; ++i) {
            a0 ^= xv[i] & g[0][i];
            a1 ^= xv[i] & g[1][i];
        }
        float2 o;
        o.x = (float)(__popc(a0) & 1);
        o.y = (float)(__popc(a1) & 1);
        reinterpret_cast<float2*>(out + (size_t)(b0 + r) * 1024)[tid] = o;
    }
}

// ---------------------------------------------------------------------------
extern "C" void kernel_launch(void* const* d_in, const int* in_sizes, int n_in,
                              void* d_out, int out_size, void* d_ws, size_t ws_size,
                              hipStream_t stream) {
    const float* x = (const float*)d_in[0];   // [B][512]
    const float* G = (const float*)d_in[1];   // [N][512]
    float* out = (float*)d_out;

    const int B = 131072;
    // Pack G: 2048 chunks, 4 chunks (waves) per block -> 512 blocks.
    unsigned long long* gp64 = (unsigned long long*)d_ws;  // 64 KiB
    pack256_kernel<<<512, 256, 0, stream>>>(G, gp64, 2048);
    // Fused pack-x + encode: one block per 64 rows.
    gf2_fused_kernel<<<B / 64, 512, 0, stream>>>(
        x, (const uint32_t*)gp64, out);
}